// Round 1
// baseline (461.395 us; speedup 1.0000x reference)
//
#include <hip/hip_runtime.h>

// ScatterND: x (1024,2048,128) f32; indices (200000,2) int; updates (200000,128) f32
// out = x; out[i0,i1,:] = updates[m,:]   (indices unique -> order-free)

#define DIM0 1024
#define DIM1 2048
#define CH   128
#define NSLICES 200000
#define VPS (CH / 4)              // 32 float4 per slice (512 B)

__global__ __launch_bounds__(256) void scatter_slices(
        const int* __restrict__ indices,
        const float4* __restrict__ updates,
        float4* __restrict__ out) {
    int tid = blockIdx.x * blockDim.x + threadIdx.x;
    const int total = NSLICES * VPS;          // 6,400,000
    if (tid >= total) return;
    int m = tid >> 5;                          // slice index
    int v = tid & (VPS - 1);                   // float4 within slice
    int i0 = indices[2 * m];
    int i1 = indices[2 * m + 1];
    int slice = i0 * DIM1 + i1;                // < 2^21
    out[slice * VPS + v] = updates[m * VPS + v];
}

extern "C" void kernel_launch(void* const* d_in, const int* in_sizes, int n_in,
                              void* d_out, int out_size, void* d_ws, size_t ws_size,
                              hipStream_t stream) {
    const void*  x       = d_in[0];
    const int*   indices = (const int*)d_in[1];
    const float4* updates = (const float4*)d_in[2];
    float4* out = (float4*)d_out;

    // 1) out = x  (1 GiB D2D copy at HBM BW)
    size_t bytes = (size_t)DIM0 * DIM1 * CH * sizeof(float);
    hipMemcpyAsync(d_out, x, bytes, hipMemcpyDeviceToDevice, stream);

    // 2) scatter the 200k slices
    const int total = NSLICES * VPS;
    const int block = 256;
    const int grid = (total + block - 1) / block;
    scatter_slices<<<grid, block, 0, stream>>>(indices, updates, out);
}

// Round 2
// 368.787 us; speedup vs baseline: 1.2511x; 1.2511x over previous
//
#include <hip/hip_runtime.h>

// ScatterND: x (1024,2048,128) f32; indices (200000,2) int32; updates (200000,128) f32
// out = x; out[i0,i1,:] = updates[m,:]   (indices unique -> order-free)
//
// Strategy: inverse-map fusion. map[slice] = m+1 (0 = not scattered), then one
// pass writes each output slice exactly once from either x or updates.
// Saves the double-write of scattered slices and the x-read for them.

#define DIM0 1024
#define DIM1 2048
#define CH   128
#define NSLICES 200000
#define NSL_TOT (DIM0 * DIM1)     // 2^21 slices
#define VPS (CH / 4)              // 32 float4 per slice (512 B)

// --- kernel 1: zero the slice->update map (8 MB, int4-vectorized) ---
__global__ __launch_bounds__(256) void init_map(int4* __restrict__ map4) {
    int i = blockIdx.x * 256 + threadIdx.x;   // NSL_TOT/4 = 524288 int4
    map4[i] = make_int4(0, 0, 0, 0);
}

// --- kernel 2: scatter m+1 into map ---
__global__ __launch_bounds__(256) void build_map(const int* __restrict__ indices,
                                                 int* __restrict__ map) {
    int m = blockIdx.x * 256 + threadIdx.x;
    if (m >= NSLICES) return;
    int i0 = indices[2 * m];
    int i1 = indices[2 * m + 1];
    map[i0 * DIM1 + i1] = m + 1;
}

// --- kernel 3: fused copy+scatter, one float4 per lane, 32 lanes per slice ---
__global__ __launch_bounds__(256) void fused_copy_scatter(
        const float4* __restrict__ x,
        const float4* __restrict__ upd,
        const int* __restrict__ map,
        float4* __restrict__ out) {
    int tid = blockIdx.x * 256 + threadIdx.x;  // NSL_TOT*VPS = 67,108,864 threads
    int slice = tid >> 5;
    int v = tid & (VPS - 1);
    int m = map[slice];                        // broadcast within each 32-lane group
    const float4* src = (m == 0) ? (x + (size_t)slice * VPS)
                                 : (upd + (size_t)(m - 1) * VPS);
    out[(size_t)slice * VPS + v] = src[v];
}

// --- fallback scatter (used only if ws too small for the map) ---
__global__ __launch_bounds__(256) void scatter_slices(
        const int* __restrict__ indices,
        const float4* __restrict__ updates,
        float4* __restrict__ out) {
    int tid = blockIdx.x * blockDim.x + threadIdx.x;
    const int total = NSLICES * VPS;
    if (tid >= total) return;
    int m = tid >> 5;
    int v = tid & (VPS - 1);
    int i0 = indices[2 * m];
    int i1 = indices[2 * m + 1];
    int slice = i0 * DIM1 + i1;
    out[(size_t)slice * VPS + v] = updates[(size_t)m * VPS + v];
}

extern "C" void kernel_launch(void* const* d_in, const int* in_sizes, int n_in,
                              void* d_out, int out_size, void* d_ws, size_t ws_size,
                              hipStream_t stream) {
    const float4* x       = (const float4*)d_in[0];
    const int*    indices = (const int*)d_in[1];
    const float4* updates = (const float4*)d_in[2];
    float4* out = (float4*)d_out;

    const size_t map_bytes = (size_t)NSL_TOT * sizeof(int);

    if (ws_size >= map_bytes) {
        int* map = (int*)d_ws;
        // 1) map = 0
        init_map<<<NSL_TOT / 4 / 256, 256, 0, stream>>>((int4*)map);
        // 2) map[slice] = m+1
        build_map<<<(NSLICES + 255) / 256, 256, 0, stream>>>(indices, map);
        // 3) out[slice] = mapped ? updates[m] : x[slice]
        const int total = NSL_TOT * VPS;
        fused_copy_scatter<<<total / 256, 256, 0, stream>>>(x, updates, map, out);
    } else {
        // fallback: copy then scatter
        size_t bytes = (size_t)DIM0 * DIM1 * CH * sizeof(float);
        hipMemcpyAsync(d_out, x, bytes, hipMemcpyDeviceToDevice, stream);
        const int total = NSLICES * VPS;
        scatter_slices<<<(total + 255) / 256, 256, 0, stream>>>(indices, updates, out);
    }
}